// Round 11
// baseline (120.142 us; speedup 1.0000x reference)
//
#include <hip/hip_runtime.h>
#include <math.h>

#define D      4096
#define NPREV  8191
#define NROWS  8192

typedef float f4 __attribute__((ext_vector_type(4)));

static __device__ __forceinline__ f4 nt_load4(const float* p) {
    return __builtin_nontemporal_load(reinterpret_cast<const f4*>(p));
}
static __device__ __forceinline__ f4 ld4(const float* p) {
    return *reinterpret_cast<const f4*>(p);
}
static __device__ __forceinline__ void st4(f4 v, float* p) {
    *reinterpret_cast<f4*>(p) = v;
}

// ---- K1/K5: out[row] = dot(W[row,:], v) (+resid). 1024 blocks x 256 ---------
template<bool RESIDUAL>
__global__ void k_matvec_rows(const float* __restrict__ W, const float* __restrict__ v,
                              const float* __restrict__ resid, float* __restrict__ out) {
    int row  = blockIdx.x * 4 + (threadIdx.x >> 6);
    int lane = threadIdx.x & 63;
    const float* Wrow = W + (size_t)row * D;
    float acc = 0.f;
    #pragma unroll
    for (int i = 0; i < 16; ++i) {
        int c = lane + i * 64;
        f4 w = nt_load4(Wrow + 4 * c);
        f4 x = ld4(v + 4 * c);
        acc += w.x * x.x + w.y * x.y + w.z * x.z + w.w * x.w;
    }
    #pragma unroll
    for (int off = 32; off; off >>= 1) acc += __shfl_down(acc, off, 64);
    if (lane == 0) out[row] = RESIDUAL ? (acc + resid[row]) : acc;
}

// ---- K2: kq[d] = sum_m q[m] * W_K[m][d]. 256 blocks x 256 -------------------
__global__ void k_kq(const float* __restrict__ W, const float* __restrict__ q,
                     float* __restrict__ kq) {
    __shared__ float s_q[D];            // 16 KB
    __shared__ f4 s_part[64][4];        // 4 KB
    int t = threadIdx.x;
    int b = blockIdx.x;
    for (int i = t; i < D; i += 256) s_q[i] = q[i];
    __syncthreads();
    int c4 = b * 4 + (t & 3);           // f4 column
    int r0 = t >> 2;                    // 0..63
    f4 acc = (f4)0.f;
    #pragma unroll 16
    for (int i = 0; i < 64; ++i) {
        int m = r0 + i * 64;
        acc += s_q[m] * nt_load4(W + (size_t)m * D + 4 * c4);
    }
    s_part[r0][t & 3] = acc;
    __syncthreads();
    if (t < 4) {
        f4 a = (f4)0.f;
        #pragma unroll
        for (int g = 0; g < 64; ++g) a += s_part[g][t];
        st4(a, kq + 4 * (b * 4 + t));
    }
}

// ---- K3 main: barrier-free wave-autonomous flash ----------------------------
// 512 blocks x 256 thr = 2048 waves; wave g owns rows {g, g+2048, g+4096,
// g+6144} sequentially. Per row: 16 f4 load -> store io -> dot vs register kq
// -> shuffle reduce -> online softmax update in registers. No __syncthreads.
#define NWAVE 2048
#define RPW   4
__global__ __launch_bounds__(256, 2) void k_flash_nb(
        const float* __restrict__ prev, const float* __restrict__ inp,
        const float* __restrict__ kq, float* __restrict__ io,
        float* __restrict__ ms, float* __restrict__ ctxpart) {
    const int t = threadIdx.x;
    const int lane = t & 63;
    const int gw = blockIdx.x * 4 + (t >> 6);     // global wave 0..2047

    f4 kqr[16];
    #pragma unroll
    for (int i = 0; i < 16; ++i) kqr[i] = ld4(kq + 4 * (lane + 64 * i));

    float m = -INFINITY, s = 0.f;
    f4 a[16];
    #pragma unroll
    for (int i = 0; i < 16; ++i) a[i] = (f4)0.f;

    for (int k = 0; k < RPW; ++k) {
        int n = gw + NWAVE * k;
        const float* src = (n < NPREV) ? (prev + (size_t)n * D) : inp;
        float* dst = io + (size_t)n * D;
        f4 x[16];
        #pragma unroll
        for (int i = 0; i < 16; ++i) x[i] = ld4(src + 4 * (lane + 64 * i));
        float p = 0.f;
        #pragma unroll
        for (int i = 0; i < 16; ++i) {
            st4(x[i], dst + 4 * (lane + 64 * i));
            p += x[i].x * kqr[i].x + x[i].y * kqr[i].y
               + x[i].z * kqr[i].z + x[i].w * kqr[i].w;
        }
        #pragma unroll
        for (int off = 32; off; off >>= 1) p += __shfl_down(p, off, 64);
        p = __shfl(p, 0, 64);                      // broadcast row logit
        if (p > m) {                               // wave-uniform rescale
            float sc = __expf(m - p);              // first row: exp(-inf)=0
            s *= sc;
            #pragma unroll
            for (int i = 0; i < 16; ++i) a[i] *= sc;
            m = p;
        }
        float e = __expf(p - m);
        s += e;
        #pragma unroll
        for (int i = 0; i < 16; ++i) a[i] += e * x[i];
    }
    float* cp = ctxpart + (size_t)gw * D;
    #pragma unroll
    for (int i = 0; i < 16; ++i) st4(a[i], cp + 4 * (lane + 64 * i));
    if (lane == 0) { ms[2 * gw] = m; ms[2 * gw + 1] = s; }
}

// ---- K3 fallback (small ws): R9 register flash. FB=512 x 1024 ---------------
#define FBR  512
#define FRR  16
__global__ __launch_bounds__(1024, 4) void k_flash_reg(
        const float* __restrict__ prev, const float* __restrict__ inp,
        const float* __restrict__ kq, float* __restrict__ io,
        float* __restrict__ ms, float* __restrict__ ctxpart) {
    __shared__ float s_wred[16][FRR];
    __shared__ float s_log[FRR];
    const int n0 = blockIdx.x * FRR;
    const int t = threadIdx.x;
    const int wid = t >> 6, lane = t & 63;
    const f4 kqv = ld4(kq + 4 * t);
    f4 x[FRR];
    #pragma unroll
    for (int r = 0; r < FRR; ++r) {
        int n = n0 + r;
        const float* src = (n < NPREV) ? (prev + (size_t)n * D) : inp;
        x[r] = ld4(src + 4 * t);
    }
    float p[FRR];
    #pragma unroll
    for (int r = 0; r < FRR; ++r) {
        int n = n0 + r;
        st4(x[r], io + (size_t)n * D + 4 * t);
        p[r] = x[r].x * kqv.x + x[r].y * kqv.y + x[r].z * kqv.z + x[r].w * kqv.w;
    }
    #pragma unroll
    for (int r = 0; r < FRR; ++r) {
        float v = p[r];
        #pragma unroll
        for (int off = 32; off; off >>= 1) v += __shfl_down(v, off, 64);
        if (lane == 0) s_wred[wid][r] = v;
    }
    __syncthreads();
    if (t < FRR) {
        float s = 0.f;
        #pragma unroll
        for (int w = 0; w < 16; ++w) s += s_wred[w][t];
        s_log[t] = s;
    }
    __syncthreads();
    float m_b = -INFINITY;
    #pragma unroll
    for (int r = 0; r < FRR; ++r) m_b = fmaxf(m_b, s_log[r]);
    float e[FRR], s_b = 0.f;
    #pragma unroll
    for (int r = 0; r < FRR; ++r) { e[r] = __expf(s_log[r] - m_b); s_b += e[r]; }
    f4 a = (f4)0.f;
    #pragma unroll
    for (int r = 0; r < FRR; ++r) a += e[r] * x[r];
    st4(a, ctxpart + (size_t)blockIdx.x * D + 4 * t);
    if (t == 0) { ms[2 * blockIdx.x] = m_b; ms[2 * blockIdx.x + 1] = s_b; }
}

// ---- K4: combine FBT partials -> normalized ctx. 64 blocks x 256 ------------
template<int FBT>
__global__ void k_combine(const float* __restrict__ ms, const float* __restrict__ ctxpart,
                          float* __restrict__ ctx) {
    constexpr int PPT = FBT / 256;      // ms pairs per thread
    constexpr int PPG = FBT / 16;       // partials per group-thread
    __shared__ float s_w[FBT];
    __shared__ float s_red[8];
    __shared__ f4 s_acc[16][16];
    int t = threadIdx.x;                // 256
    int lane = t & 63, wid = t >> 6;
    float mloc[PPT];
    float mx = -INFINITY;
    #pragma unroll
    for (int k = 0; k < PPT; ++k) { mloc[k] = ms[2 * (t + 256 * k)]; mx = fmaxf(mx, mloc[k]); }
    #pragma unroll
    for (int off = 32; off; off >>= 1) mx = fmaxf(mx, __shfl_down(mx, off, 64));
    if (lane == 0) s_red[wid] = mx;
    __syncthreads();
    float M = fmaxf(fmaxf(s_red[0], s_red[1]), fmaxf(s_red[2], s_red[3]));
    float sc = 0.f;
    #pragma unroll
    for (int k = 0; k < PPT; ++k) {
        float w = __expf(mloc[k] - M);
        s_w[t + 256 * k] = w;
        sc += w * ms[2 * (t + 256 * k) + 1];
    }
    #pragma unroll
    for (int off = 32; off; off >>= 1) sc += __shfl_down(sc, off, 64);
    if (lane == 0) s_red[4 + wid] = sc;
    __syncthreads();
    float S = s_red[4] + s_red[5] + s_red[6] + s_red[7];
    int c = t & 15, g = t >> 4;
    int col4 = blockIdx.x * 16 + c;
    f4 a = (f4)0.f;
    #pragma unroll 8
    for (int i = 0; i < PPG; ++i) {
        int pp = g * PPG + i;
        a += s_w[pp] * ld4(ctxpart + (size_t)pp * D + 4 * col4);
    }
    s_acc[g][c] = a;
    __syncthreads();
    if (t < 16) {
        f4 aa = (f4)0.f;
        #pragma unroll
        for (int gg = 0; gg < 16; ++gg) aa += s_acc[gg][t];
        st4(aa * (1.f / S), ctx + 4 * (blockIdx.x * 16 + t));
    }
}

extern "C" void kernel_launch(void* const* d_in, const int* in_sizes, int n_in,
                              void* d_out, int out_size, void* d_ws, size_t ws_size,
                              hipStream_t stream) {
    const float* prev = (const float*)d_in[0];   // (8191, 4096)
    const float* inp  = (const float*)d_in[1];   // (4096,)
    const float* W_Q  = (const float*)d_in[2];
    const float* W_K  = (const float*)d_in[3];
    const float* W_V  = (const float*)d_in[4];
    float* out = (float*)d_out;                  // [0:4096]=output, [4096:]=inputs
    float* io  = out + D;
    float* ws  = (float*)d_ws;

    // main ws: q D | kq D | ms 2*NWAVE | ctxpart NWAVE*D | ctx D (~33.6 MB)
    size_t need_main = (size_t)(2 * D + 2 * NWAVE + (size_t)NWAVE * D + D) * sizeof(float);

    float* q  = ws;
    float* kq = q + D;
    float* ms = kq + D;

    if (ws_size >= need_main) {
        float* ctxpart = ms + 2 * NWAVE;
        float* ctx     = ctxpart + (size_t)NWAVE * D;
        k_matvec_rows<false><<<1024, 256, 0, stream>>>(W_Q, inp, nullptr, q);
        k_kq<<<256, 256, 0, stream>>>(W_K, q, kq);
        k_flash_nb<<<512, 256, 0, stream>>>(prev, inp, kq, io, ms, ctxpart);
        k_combine<NWAVE><<<64, 256, 0, stream>>>(ms, ctxpart, ctx);
        k_matvec_rows<true><<<1024, 256, 0, stream>>>(W_V, ctx, inp, out);
    } else {
        // fallback: R9-proven register flash (~8.4 MB ws)
        float* ctxpart = ms + 2 * FBR;
        float* ctx     = ctxpart + (size_t)FBR * D;
        k_matvec_rows<false><<<1024, 256, 0, stream>>>(W_Q, inp, nullptr, q);
        k_kq<<<256, 256, 0, stream>>>(W_K, q, kq);
        k_flash_reg<<<FBR, 1024, 0, stream>>>(prev, inp, kq, io, ms, ctxpart);
        k_combine<FBR><<<64, 256, 0, stream>>>(ms, ctxpart, ctx);
        k_matvec_rows<true><<<1024, 256, 0, stream>>>(W_V, ctx, inp, out);
    }
}